// Round 10
// baseline (430.213 us; speedup 1.0000x reference)
//
#include <hip/hip_runtime.h>

typedef __attribute__((ext_vector_type(4))) float f32x4;
typedef __attribute__((ext_vector_type(8))) short bf16x8;
typedef unsigned short u16;

constexpr int kB = 2, kS = 2048, kD = 1024, kH = 16, kHD = 64, kHID = 3584;
constexpr int kN = kB * kS;  // 4096 tokens

__device__ __forceinline__ u16 f2bf(float f) {
  unsigned u = __float_as_uint(f);
  u = (u + 0x7FFFu + ((u >> 16) & 1u)) >> 16;
  return (u16)u;
}
__device__ __forceinline__ float bf2f(u16 v) {
  return __uint_as_float((unsigned)v << 16);
}

// 16-lane (DPP row) max reduction: row_ror 1,2,4,8 + fmax. VALU-only.
__device__ __forceinline__ float rowmax16(float v) {
  int t;
  t = __builtin_amdgcn_update_dpp(0, __float_as_int(v), 0x121, 0xf, 0xf, true);
  v = fmaxf(v, __int_as_float(t));
  t = __builtin_amdgcn_update_dpp(0, __float_as_int(v), 0x122, 0xf, 0xf, true);
  v = fmaxf(v, __int_as_float(t));
  t = __builtin_amdgcn_update_dpp(0, __float_as_int(v), 0x124, 0xf, 0xf, true);
  v = fmaxf(v, __int_as_float(t));
  t = __builtin_amdgcn_update_dpp(0, __float_as_int(v), 0x128, 0xf, 0xf, true);
  v = fmaxf(v, __int_as_float(t));
  return v;
}

#define AS1(p) ((const __attribute__((address_space(1))) void*)(p))
#define AS3(p) ((__attribute__((address_space(3))) void*)(p))

// ---------------------------------------------------------------- prep: x+pos, RMSNorm1
__global__ __launch_bounds__(256) void k_prep(
    const float* __restrict__ x, const float* __restrict__ pos,
    const float* __restrict__ w, float* __restrict__ xr, u16* __restrict__ xn) {
  const int n = blockIdx.x, t = threadIdx.x, s = n & (kS - 1);
  float4 a = ((const float4*)(x + (size_t)n * kD))[t];
  float4 p = ((const float4*)(pos + (size_t)s * kD))[t];
  a.x += p.x; a.y += p.y; a.z += p.z; a.w += p.w;
  ((float4*)(xr + (size_t)n * kD))[t] = a;
  float ss = a.x*a.x + a.y*a.y + a.z*a.z + a.w*a.w;
#pragma unroll
  for (int off = 1; off < 64; off <<= 1) ss += __shfl_xor(ss, off);
  __shared__ float red[4];
  if ((t & 63) == 0) red[t >> 6] = ss;
  __syncthreads();
  float rs = rsqrtf((red[0] + red[1] + red[2] + red[3]) * (1.0f / kD) + 1e-6f);
  float4 wv = ((const float4*)w)[t];
  ushort4 o;
  o.x = f2bf(a.x * rs * wv.x); o.y = f2bf(a.y * rs * wv.y);
  o.z = f2bf(a.z * rs * wv.z); o.w = f2bf(a.w * rs * wv.w);
  ((ushort4*)(xn + (size_t)n * kD))[t] = o;
}

// ---------------------------------------------------------------- RMSNorm2
__global__ __launch_bounds__(256) void k_rms2(
    const float* __restrict__ xin, const float* __restrict__ w, u16* __restrict__ xn) {
  const int n = blockIdx.x, t = threadIdx.x;
  float4 a = ((const float4*)(xin + (size_t)n * kD))[t];
  float ss = a.x*a.x + a.y*a.y + a.z*a.z + a.w*a.w;
#pragma unroll
  for (int off = 1; off < 64; off <<= 1) ss += __shfl_xor(ss, off);
  __shared__ float red[4];
  if ((t & 63) == 0) red[t >> 6] = ss;
  __syncthreads();
  float rs = rsqrtf((red[0] + red[1] + red[2] + red[3]) * (1.0f / kD) + 1e-6f);
  float4 wv = ((const float4*)w)[t];
  ushort4 o;
  o.x = f2bf(a.x * rs * wv.x); o.y = f2bf(a.y * rs * wv.y);
  o.z = f2bf(a.z * rs * wv.z); o.w = f2bf(a.w * rs * wv.w);
  ((ushort4*)(xn + (size_t)n * kD))[t] = o;
}

// ---------------------------------------------------------------- fused weight prep
__device__ __forceinline__ void cvt4(const float* __restrict__ s, u16* __restrict__ d, int j) {
  float4 v = ((const float4*)s)[j];
  ushort4 o;
  o.x = f2bf(v.x); o.y = f2bf(v.y); o.z = f2bf(v.z); o.w = f2bf(v.w);
  ((ushort4*)d)[j] = o;
}

__global__ __launch_bounds__(256) void k_wprep(
    const float* __restrict__ q_w, const float* __restrict__ k_w,
    const float* __restrict__ v_w, const float* __restrict__ o_w,
    const float* __restrict__ in_w, const float* __restrict__ gate_w,
    const float* __restrict__ out_w,
    const float* __restrict__ q_b, const float* __restrict__ k_b,
    const float* __restrict__ v_b,
    u16* __restrict__ W, float* __restrict__ bqkv) {
  const int i = blockIdx.x * 256 + threadIdx.x;
  if (i < 262144)       cvt4(q_w,    W + 0,        i);
  else if (i < 524288)  cvt4(k_w,    W + 1048576,  i - 262144);
  else if (i < 786432)  cvt4(v_w,    W + 2097152,  i - 524288);
  else if (i < 1048576) cvt4(o_w,    W + 3145728,  i - 786432);
  else if (i < 1966080) cvt4(in_w,   W + 4194304,  i - 1048576);
  else if (i < 2883584) cvt4(gate_w, W + 7864320,  i - 1966080);
  else if (i < 3801088) cvt4(out_w,  W + 11534336, i - 2883584);
  else {
    const int j = i - 3801088;  // 0..767
    const float* src = j < 256 ? q_b : (j < 512 ? k_b : v_b);
    ((float4*)bqkv)[j] = ((const float4*)src)[j & 255];
  }
}

// ---------------------------------------------------------------- GEMM: C = A(bf16,MxK) * B(bf16,NxK)^T + bias
// Round-5 2-phase + 2D XCD chunk (XCD grid 2x4, nR rows x nC cols per XCD,
// row-fastest so the current B col-panel stays L2-resident).
// MODE 0: out bf16 = acc + bias
// MODE 1: out fp32 = acc + bias + f32 extra[idx]   (residual)
template <int MODE, int BM>
__global__ __launch_bounds__(256) void k_gemm(
    const u16* __restrict__ A, const u16* __restrict__ Bw,
    const float* __restrict__ bias, const void* extra,
    void* outp, int M, int N, int K, int nR, int nC) {
  constexpr int ASEG = BM / 16;      // 1024B segments in A tile
  constexpr int NSEG = ASEG + 8;
  constexpr int WROWS = BM / 2;
  constexpr int MF = BM / 32;
  __shared__ __align__(16) u16 As[2][BM * 32];
  __shared__ __align__(16) u16 Bs[2][128 * 32];
  const int tid = threadIdx.x, lane = tid & 63, wv_ = tid >> 6;
  const int lr = lane & 15, lg = lane >> 4;
  const int xcd = blockIdx.x & 7, idx = blockIdx.x >> 3;
  const int xrr = xcd >> 2, xcc = xcd & 3;         // 2x4 XCD grid
  const int r_ = idx % nR, c_ = idx / nR;          // row-fastest
  const int brow = (xrr * nR + r_) * BM, bcol = (xcc * nC + c_) * 128;
  const int wr = wv_ >> 1, wc = wv_ & 1;

  const f32x4 zz = {0.f, 0.f, 0.f, 0.f};
  f32x4 acc[MF][4];
#pragma unroll
  for (int m = 0; m < MF; m++)
#pragma unroll
    for (int n = 0; n < 4; n++) acc[m][n] = zz;

  auto stage = [&](int kt, int buf) {
#pragma unroll
    for (int i = 0; i < NSEG / 4; ++i) {
      const int seg = i * 4 + wv_;
      const int rsub = (seg < ASEG) ? seg : seg - ASEG;
      const int row = rsub * 16 + (lane >> 2), cs = lane & 3;
      if (seg < ASEG) {
        __builtin_amdgcn_global_load_lds(AS1(A + (size_t)(brow + row) * K + kt + cs * 8),
                                         AS3((char*)&As[buf][0] + (size_t)seg * 1024), 16, 0, 0);
      } else {
        __builtin_amdgcn_global_load_lds(AS1(Bw + (size_t)(bcol + row) * K + kt + cs * 8),
                                         AS3((char*)&Bs[buf][0] + (size_t)(seg - ASEG) * 1024), 16, 0, 0);
      }
    }
  };

  stage(0, 0);
  __syncthreads();
  for (int kt = 0; kt < K; kt += 32) {
    const int cur = (kt >> 5) & 1;
    if (kt + 32 < K) stage(kt + 32, cur ^ 1);   // in flight under compute
    bf16x8 af[MF], bfr[4];
#pragma unroll
    for (int m = 0; m < MF; m++) af[m] = *(const bf16x8*)&As[cur][(wr * WROWS + m * 16 + lr) * 32 + lg * 8];
#pragma unroll
    for (int n = 0; n < 4; n++) bfr[n] = *(const bf16x8*)&Bs[cur][(wc * 64 + n * 16 + lr) * 32 + lg * 8];
#pragma unroll
    for (int m = 0; m < MF; m++)
#pragma unroll
      for (int n = 0; n < 4; n++)
        acc[m][n] = __builtin_amdgcn_mfma_f32_16x16x32_bf16(af[m], bfr[n], acc[m][n], 0, 0, 0);
    __syncthreads();   // reads of cur retired; next-tile loads drained (covered by compute)
  }

  // epilogue: C layout col=lane&15, row=(lane>>4)*4+reg  [m89-verified]
#pragma unroll
  for (int m = 0; m < MF; m++) {
    const int row0 = brow + wr * WROWS + m * 16 + lg * 4;
#pragma unroll
    for (int n = 0; n < 4; n++) {
      const int col = bcol + wc * 64 + n * 16 + lr;
      const float bv = bias[col];
#pragma unroll
      for (int r = 0; r < 4; r++) {
        const size_t idx2 = (size_t)(row0 + r) * N + col;
        float v = acc[m][n][r] + bv;
        if (MODE == 0) {
          ((u16*)outp)[idx2] = f2bf(v);
        } else {
          ((float*)outp)[idx2] = v + ((const float*)extra)[idx2];
        }
      }
    }
  }
}

// ---------------------------------------------------------------- fused MLP in+gate GEMM
// out = silu(A*Wg^T + gate_b) * (A*Win^T + in_b), bf16. A staged once for both B's.
// 2D XCD chunk 16x7 row-fastest (round-9 verified: FETCH 212->47MB, 145->87.5us).
__global__ __launch_bounds__(256, 2) void k_mlp(
    const u16* __restrict__ A, const u16* __restrict__ Bi, const u16* __restrict__ Bg,
    const float* __restrict__ bias_i, const float* __restrict__ bias_g,
    u16* __restrict__ outp, int M, int N, int K) {
  __shared__ __align__(16) u16 AsT[2][128 * 32];
  __shared__ __align__(16) u16 BiT[2][128 * 32];
  __shared__ __align__(16) u16 BgT[2][128 * 32];
  const int tid = threadIdx.x, lane = tid & 63, wv_ = tid >> 6;
  const int lr = lane & 15, lg = lane >> 4;
  const int xcd = blockIdx.x & 7, idx = blockIdx.x >> 3;
  const int xrr = xcd >> 2, xcc = xcd & 3;         // 2 x 4 XCD grid
  const int r_ = idx & 15, c_ = idx >> 4;          // 16 rows x 7 cols, row-fastest
  const int brow = (xrr * 16 + r_) * 128, bcol = (xcc * 7 + c_) * 128;
  const int wr = wv_ >> 1, wc = wv_ & 1;

  const f32x4 zz = {0.f, 0.f, 0.f, 0.f};
  f32x4 accI[4][4], accG[4][4];
#pragma unroll
  for (int m = 0; m < 4; m++)
#pragma unroll
    for (int n = 0; n < 4; n++) { accI[m][n] = zz; accG[m][n] = zz; }

  auto stage = [&](int kt, int buf) {
#pragma unroll
    for (int i = 0; i < 6; ++i) {
      const int seg = i * 4 + wv_;          // i fixed per unroll => src/dst compile-time per i
      const int rsub = seg & 7;
      const int row = rsub * 16 + (lane >> 2), cs = lane & 3;
      const u16* src = (i < 2) ? A : (i < 4 ? Bi : Bg);
      char* dst = (i < 2) ? (char*)&AsT[buf][0] : (i < 4 ? (char*)&BiT[buf][0] : (char*)&BgT[buf][0]);
      __builtin_amdgcn_global_load_lds(
          AS1(src + (size_t)((i < 2 ? brow : bcol) + row) * K + kt + cs * 8),
          AS3(dst + (size_t)rsub * 1024), 16, 0, 0);
    }
  };

  stage(0, 0);
  __syncthreads();
  for (int kt = 0; kt < K; kt += 32) {
    const int cur = (kt >> 5) & 1;
    if (kt + 32 < K) stage(kt + 32, cur ^ 1);
    bf16x8 af[4], bfi[4], bfg[4];
#pragma unroll
    for (int m = 0; m < 4; m++) af[m] = *(const bf16x8*)&AsT[cur][(wr * 64 + m * 16 + lr) * 32 + lg * 8];
#pragma unroll
    for (int n = 0; n < 4; n++) {
      bfi[n] = *(const bf16x8*)&BiT[cur][(wc * 64 + n * 16 + lr) * 32 + lg * 8];
      bfg[n] = *(const bf16x8*)&BgT[cur][(wc * 64 + n * 16 + lr) * 32 + lg * 8];
    }
#pragma unroll
    for (int m = 0; m < 4; m++)
#pragma unroll
      for (int n = 0; n < 4; n++) {
        accI[m][n] = __builtin_amdgcn_mfma_f32_16x16x32_bf16(af[m], bfi[n], accI[m][n], 0, 0, 0);
        accG[m][n] = __builtin_amdgcn_mfma_f32_16x16x32_bf16(af[m], bfg[n], accG[m][n], 0, 0, 0);
      }
    __syncthreads();
  }

#pragma unroll
  for (int m = 0; m < 4; m++) {
    const int row0 = brow + wr * 64 + m * 16 + lg * 4;
#pragma unroll
    for (int n = 0; n < 4; n++) {
      const int col = bcol + wc * 64 + n * 16 + lr;
      const float bi = bias_i[col], bg = bias_g[col];
#pragma unroll
      for (int r = 0; r < 4; r++) {
        const float vi = accI[m][n][r] + bi;
        const float vg = accG[m][n][r] + bg;
        const float g = vg / (1.0f + __expf(-vg));
        outp[(size_t)(row0 + r) * N + col] = f2bf(g * vi);
      }
    }
  }
}

// ---------------------------------------------------------------- flash attention (causal, paired q-blocks, 8 waves)
// grid: 1D 512 with complementary-p mapping: bids <256 get p=bid&15, bids >=256 get
// 15-p (bh+16). Under XCD round-robin a CU's two resident blocks have complementary p
// => per-CU iteration load is the constant 49 (removes the 17..32 tail imbalance).
// Waves 0-3 own q-block 31-p, waves 4-7 own q-block p; shared KV stream.
__global__ __launch_bounds__(512) void k_attn(
    const u16* __restrict__ qkv, u16* __restrict__ attn_o) {
  __shared__ __align__(16) u16 Ks[2][64 * 64];  // [kv][d] byte = kv*128+d*2 ^ ((kv&7)<<4)
  __shared__ __align__(16) u16 Vt[2][64 * 64];  // [d][kv] byte = d*128+kv*2 ^ ((d&7)<<4)
  __shared__ __align__(16) u16 Pl[8][16 * 64];  // per-wave [q][k] swizzled

  const int tid = threadIdx.x, lane = tid & 63, w = tid >> 6;
  const int g = w >> 2, wi = w & 3;
  const int lr = lane & 15, lg = lane >> 4;
  const int bid = blockIdx.x;
  const int half = bid >> 8, rr = bid & 255;
  const int praw = rr & 15;
  const int p = half ? 15 - praw : praw;
  const int bh = (rr >> 4) | (half << 4);
  const int b = bh >> 4, h = bh & 15;
  const int qb = g == 0 ? 31 - p : p;
  const size_t base = (size_t)b * kS;
  const f32x4 zz = {0.f, 0.f, 0.f, 0.f};
  bf16x8 vones;
#pragma unroll
  for (int j = 0; j < 8; j++) vones[j] = (short)0x3F80;

  bf16x8 qf[2];
#pragma unroll
  for (int ks = 0; ks < 2; ks++)
    qf[ks] = *(const bf16x8*)&qkv[(base + qb * 64 + wi * 16 + lr) * 3072 + h * 64 + ks * 32 + lg * 8];

  f32x4 oacc[4], lacc = zz;
  float mrow[4];
#pragma unroll
  for (int nb = 0; nb < 4; nb++) oacc[nb] = zz;
#pragma unroll
  for (int r = 0; r < 4; r++) mrow[r] = -1e30f;

  const int kvloc = (w << 3) + (lane >> 3);
  const int kchv = ((lane & 7) ^ (lane >> 3)) * 8;
  auto issueK = [&](int t, int buf) {
    __builtin_amdgcn_global_load_lds(
        AS1(qkv + (base + t * 64 + kvloc) * 3072 + 1024 + h * 64 + kchv),
        AS3((char*)&Ks[buf][0] + w * 1024 + (size_t)lane * 16), 16, 0, 0);
  };
  const int srow = tid >> 3, dc = (tid & 7) * 8;
  int4 vr;
  auto issueV = [&](int t) {
    vr = *(const int4*)&qkv[(base + t * 64 + srow) * 3072 + 2048 + h * 64 + dc];
  };
  auto commitV = [&](int buf) {
    char* vb = (char*)&Vt[buf][0];
    const u16* ve = (const u16*)&vr;
#pragma unroll
    for (int j = 0; j < 8; j++) {
      const int d = dc + j;
      *(u16*)(vb + ((d * 128 + srow * 2) ^ ((d & 7) << 4))) = ve[j];
    }
  };

  auto compute = [&](int t, int buf) {
    const char* kbuf = (const char*)&Ks[buf][0];
    const char* vbuf = (const char*)&Vt[buf][0];
    const bool masked = (t == qb);
    f32x4 sc[4];
#pragma unroll
    for (int hn = 0; hn < 4; hn++) sc[hn] = zz;
#pragma unroll
    for (int hn = 0; hn < 4; hn++) {
      const int krow = hn * 16 + lr;
#pragma unroll
      for (int ks = 0; ks < 2; ks++) {
        const int bo = (krow * 128 + (ks * 32 + lg * 8) * 2) ^ ((krow & 7) << 4);
        bf16x8 kf = *(const bf16x8*)(kbuf + bo);
        sc[hn] = __builtin_amdgcn_mfma_f32_16x16x32_bf16(qf[ks], kf, sc[hn], 0, 0, 0);
      }
    }
    float alpha[4];
#pragma unroll
    for (int r = 0; r < 4; r++) {
      const int qa = qb * 64 + wi * 16 + lg * 4 + r;
      float s0 = sc[0][r] * 0.125f, s1 = sc[1][r] * 0.125f;
      float s2 = sc[2][r] * 0.125f, s3 = sc[3][r] * 0.125f;
      if (masked) {
        if (t * 64 + lr > qa) s0 = -1e30f;
        if (t * 64 + 16 + lr > qa) s1 = -1e30f;
        if (t * 64 + 32 + lr > qa) s2 = -1e30f;
        if (t * 64 + 48 + lr > qa) s3 = -1e30f;
      }
      float mx = rowmax16(fmaxf(fmaxf(s0, s1), fmaxf(s2, s3)));
      const float mnew = fmaxf(mrow[r], mx);
      alpha[r] = __expf(mrow[r] - mnew);
      mrow[r] = mnew;
      sc[0][r] = __expf(s0 - mnew); sc[1][r] = __expf(s1 - mnew);
      sc[2][r] = __expf(s2 - mnew); sc[3][r] = __expf(s3 - mnew);
    }
#pragma unroll
    for (int nb = 0; nb < 4; nb++)
#pragma unroll
      for (int r = 0; r < 4; r++) oacc[nb][r] *= alpha[r];
#pragma unroll
    for (int r = 0; r < 4; r++) lacc[r] *= alpha[r];
    char* pw = (char*)&Pl[w][0];
#pragma unroll
    for (int hn = 0; hn < 4; hn++)
#pragma unroll
      for (int r = 0; r < 4; r++) {
        const int prow = lg * 4 + r, pcol = hn * 16 + lr;
        *(u16*)(pw + ((prow * 128 + pcol * 2) ^ ((prow & 7) << 4))) = f2bf(sc[hn][r]);
      }
    bf16x8 pf[2];
#pragma unroll
    for (int ks = 0; ks < 2; ks++)
      pf[ks] = *(const bf16x8*)((const char*)pw + ((lr * 128 + (ks * 32 + lg * 8) * 2) ^ ((lr & 7) << 4)));
#pragma unroll
    for (int nb = 0; nb < 4; nb++) {
      const int vrow = nb * 16 + lr;
#pragma unroll
      for (int ks = 0; ks < 2; ks++) {
        const int bo = (vrow * 128 + (ks * 32 + lg * 8) * 2) ^ ((vrow & 7) << 4);
        bf16x8 vf = *(const bf16x8*)(vbuf + bo);
        oacc[nb] = __builtin_amdgcn_mfma_f32_16x16x32_bf16(pf[ks], vf, oacc[nb], 0, 0, 0);
      }
    }
#pragma unroll
    for (int ks = 0; ks < 2; ks++)
      lacc = __builtin_amdgcn_mfma_f32_16x16x32_bf16(pf[ks], vones, lacc, 0, 0, 0);
  };

  const int nt = 32 - p;
  issueV(0);
  issueK(0, 0);
  commitV(0);
  __syncthreads();
  for (int t = 0; t < nt; ++t) {
    const bool hn = (t + 1 < nt);
    const int buf = t & 1;
    if (hn) { issueV(t + 1); issueK(t + 1, buf ^ 1); }
    if (g == 0 || t <= p) compute(t, buf);
    if (hn) commitV(buf ^ 1);        // idle buffer: no read hazard, pre-barrier
    __syncthreads();                 // K(t+1) drained (covered by compute); V(t+1) visible
  }

#pragma unroll
  for (int nb = 0; nb < 4; nb++)
#pragma unroll
    for (int r = 0; r < 4; r++) {
      const int q = qb * 64 + wi * 16 + lg * 4 + r;
      attn_o[(base + q) * kD + h * 64 + nb * 16 + lr] = f2bf(oacc[nb][r] / lacc[r]);
    }
}

// ---------------------------------------------------------------- workspace layout (bytes)
constexpr size_t OFF_XR   = 0;                                   // fp32 [4096][1024]
constexpr size_t OFF_XN1  = OFF_XR  + (size_t)kN * kD * 4;       // bf16 [4096][1024]
constexpr size_t OFF_XN2  = OFF_XN1 + (size_t)kN * kD * 2;       // bf16 [4096][1024]
constexpr size_t OFF_W    = OFF_XN2 + (size_t)kN * kD * 2;       // bf16 weight arena
constexpr size_t OFF_BQKV = OFF_W + 15204352ull * 2;             // fp32 [3072]
constexpr size_t OFF_ACT  = OFF_BQKV + 3072 * 4;                 // activation arena
// phase 1: qkv bf16 [4096][3072] @ +0 ; attn_o bf16 [4096][1024] @ +25165824
// phase 2: hb bf16 [4096][3584] @ +0   (qkv/attn_o dead by then)

extern "C" void kernel_launch(void* const* d_in, const int* in_sizes, int n_in,
                              void* d_out, int out_size, void* d_ws, size_t ws_size,
                              hipStream_t stream) {
  const float* x     = (const float*)d_in[0];
  const float* pos   = (const float*)d_in[1];
  const float* n1w   = (const float*)d_in[2];
  const float* n2w   = (const float*)d_in[3];
  const float* q_w   = (const float*)d_in[4];
  const float* q_b   = (const float*)d_in[5];
  const float* k_w   = (const float*)d_in[6];
  const float* k_b   = (const float*)d_in[7];
  const float* v_w   = (const float*)d_in[8];
  const float* v_b   = (const float*)d_in[9];
  const float* o_w   = (const float*)d_in[10];
  const float* o_b   = (const float*)d_in[11];
  const float* in_w  = (const float*)d_in[12];
  const float* in_b  = (const float*)d_in[13];
  const float* gate_w= (const float*)d_in[14];
  const float* gate_b= (const float*)d_in[15];
  const float* out_w = (const float*)d_in[16];
  const float* out_b = (const float*)d_in[17];
  float* outf = (float*)d_out;
  char* ws = (char*)d_ws;

  float* xr   = (float*)(ws + OFF_XR);
  u16*   xn1  = (u16*)(ws + OFF_XN1);
  u16*   xn2  = (u16*)(ws + OFF_XN2);
  u16*   W    = (u16*)(ws + OFF_W);
  float* bqkv = (float*)(ws + OFF_BQKV);
  u16*   qkv  = (u16*)(ws + OFF_ACT);
  u16*   attn_o = (u16*)(ws + OFF_ACT + (size_t)kN * 3072 * 2);
  u16*   hb     = (u16*)(ws + OFF_ACT);

  // weight arena offsets (u16)
  u16* Wq   = W + 0;
  u16* Wo   = W + 3145728;
  u16* Win  = W + 4194304;
  u16* Wg   = W + 7864320;
  u16* Wout = W + 11534336;

  // 1. pos add + RMSNorm1 ; fused weight conversion
  k_prep<<<kN, 256, 0, stream>>>(x, pos, n1w, xr, xn1);
  k_wprep<<<14851, 256, 0, stream>>>(q_w, k_w, v_w, o_w, in_w, gate_w, out_w,
                                     q_b, k_b, v_b, W, bqkv);

  // 2. QKV projection -> qkv bf16 [4096][3072]  (XCD 2x4, 16 rows x 6 cols each)
  k_gemm<0, 128><<<768, 256, 0, stream>>>(xn1, Wq, bqkv, nullptr, qkv, kN, 3072, kD, 16, 6);

  // 3. attention (complementary-p paired blocks, 8 waves, 1 barrier/tile)
  k_attn<<<512, 512, 0, stream>>>(qkv, attn_o);

  // 4. O projection + residual -> d_out fp32  (XCD 2x4, 32 rows x 2 cols each)
  k_gemm<1, 64><<<512, 256, 0, stream>>>(attn_o, Wo, o_b, xr, outf, kN, kD, kD, 32, 2);

  // 5. RMSNorm2
  k_rms2<<<kN, 256, 0, stream>>>(outf, n2w, xn2);

  // 6. fused MLP in+gate -> hb bf16 [4096][3584]
  k_mlp<<<896, 256, 0, stream>>>(xn2, Win, Wg, in_b, gate_b, hb, kN, kHID, kD);

  // 7. MLP out GEMM + residual -> d_out  (XCD 2x4, 32 rows x 2 cols each)
  k_gemm<1, 64><<<512, 256, 0, stream>>>(hb, Wout, out_b, outf, outf, kN, kD, kHID, 32, 2);
}

// Round 12
// 410.553 us; speedup vs baseline: 1.0479x; 1.0479x over previous
//
#include <hip/hip_runtime.h>

typedef __attribute__((ext_vector_type(4))) float f32x4;
typedef __attribute__((ext_vector_type(8))) short bf16x8;
typedef unsigned short u16;

constexpr int kB = 2, kS = 2048, kD = 1024, kH = 16, kHD = 64, kHID = 3584;
constexpr int kN = kB * kS;  // 4096 tokens

__device__ __forceinline__ u16 f2bf(float f) {
  unsigned u = __float_as_uint(f);
  u = (u + 0x7FFFu + ((u >> 16) & 1u)) >> 16;
  return (u16)u;
}
__device__ __forceinline__ float bf2f(u16 v) {
  return __uint_as_float((unsigned)v << 16);
}

// 16-lane (DPP row) max reduction: row_ror 1,2,4,8 + fmax. VALU-only.
__device__ __forceinline__ float rowmax16(float v) {
  int t;
  t = __builtin_amdgcn_update_dpp(0, __float_as_int(v), 0x121, 0xf, 0xf, true);
  v = fmaxf(v, __int_as_float(t));
  t = __builtin_amdgcn_update_dpp(0, __float_as_int(v), 0x122, 0xf, 0xf, true);
  v = fmaxf(v, __int_as_float(t));
  t = __builtin_amdgcn_update_dpp(0, __float_as_int(v), 0x124, 0xf, 0xf, true);
  v = fmaxf(v, __int_as_float(t));
  t = __builtin_amdgcn_update_dpp(0, __float_as_int(v), 0x128, 0xf, 0xf, true);
  v = fmaxf(v, __int_as_float(t));
  return v;
}

#define AS1(p) ((const __attribute__((address_space(1))) void*)(p))
#define AS3(p) ((__attribute__((address_space(3))) void*)(p))

// ---------------------------------------------------------------- fused: x+pos+RMSNorm1  AND  weight fp32->bf16
__device__ __forceinline__ void cvt4(const float* __restrict__ s, u16* __restrict__ d, int j) {
  float4 v = ((const float4*)s)[j];
  ushort4 o;
  o.x = f2bf(v.x); o.y = f2bf(v.y); o.z = f2bf(v.z); o.w = f2bf(v.w);
  ((ushort4*)d)[j] = o;
}

__global__ __launch_bounds__(256) void k_prepw(
    const float* __restrict__ x, const float* __restrict__ pos,
    const float* __restrict__ n1w, float* __restrict__ xr, u16* __restrict__ xn,
    const float* __restrict__ q_w, const float* __restrict__ k_w,
    const float* __restrict__ v_w, const float* __restrict__ o_w,
    const float* __restrict__ in_w, const float* __restrict__ gate_w,
    const float* __restrict__ out_w,
    const float* __restrict__ q_b, const float* __restrict__ k_b,
    const float* __restrict__ v_b,
    u16* __restrict__ W, float* __restrict__ bqkv) {
  __shared__ float red[4];
  if (blockIdx.x < (unsigned)kN) {
    const int n = blockIdx.x, t = threadIdx.x, s = n & (kS - 1);
    float4 a = ((const float4*)(x + (size_t)n * kD))[t];
    float4 p = ((const float4*)(pos + (size_t)s * kD))[t];
    a.x += p.x; a.y += p.y; a.z += p.z; a.w += p.w;
    ((float4*)(xr + (size_t)n * kD))[t] = a;
    float ss = a.x*a.x + a.y*a.y + a.z*a.z + a.w*a.w;
#pragma unroll
    for (int off = 1; off < 64; off <<= 1) ss += __shfl_xor(ss, off);
    if ((t & 63) == 0) red[t >> 6] = ss;
    __syncthreads();
    float rs = rsqrtf((red[0] + red[1] + red[2] + red[3]) * (1.0f / kD) + 1e-6f);
    float4 wv = ((const float4*)n1w)[t];
    ushort4 o;
    o.x = f2bf(a.x * rs * wv.x); o.y = f2bf(a.y * rs * wv.y);
    o.z = f2bf(a.z * rs * wv.z); o.w = f2bf(a.w * rs * wv.w);
    ((ushort4*)(xn + (size_t)n * kD))[t] = o;
  } else {
    const int i = (blockIdx.x - kN) * 256 + threadIdx.x;
    if (i < 262144)       cvt4(q_w,    W + 0,        i);
    else if (i < 524288)  cvt4(k_w,    W + 1048576,  i - 262144);
    else if (i < 786432)  cvt4(v_w,    W + 2097152,  i - 524288);
    else if (i < 1048576) cvt4(o_w,    W + 3145728,  i - 786432);
    else if (i < 1966080) cvt4(in_w,   W + 4194304,  i - 1048576);
    else if (i < 2883584) cvt4(gate_w, W + 7864320,  i - 1966080);
    else if (i < 3801088) cvt4(out_w,  W + 11534336, i - 2883584);
    else {
      const int j = i - 3801088;  // 0..767
      const float* src = j < 256 ? q_b : (j < 512 ? k_b : v_b);
      ((float4*)bqkv)[j] = ((const float4*)src)[j & 255];
    }
  }
}

// ---------------------------------------------------------------- RMSNorm2
__global__ __launch_bounds__(256) void k_rms2(
    const float* __restrict__ xin, const float* __restrict__ w, u16* __restrict__ xn) {
  const int n = blockIdx.x, t = threadIdx.x;
  float4 a = ((const float4*)(xin + (size_t)n * kD))[t];
  float ss = a.x*a.x + a.y*a.y + a.z*a.z + a.w*a.w;
#pragma unroll
  for (int off = 1; off < 64; off <<= 1) ss += __shfl_xor(ss, off);
  __shared__ float red[4];
  if ((t & 63) == 0) red[t >> 6] = ss;
  __syncthreads();
  float rs = rsqrtf((red[0] + red[1] + red[2] + red[3]) * (1.0f / kD) + 1e-6f);
  float4 wv = ((const float4*)w)[t];
  ushort4 o;
  o.x = f2bf(a.x * rs * wv.x); o.y = f2bf(a.y * rs * wv.y);
  o.z = f2bf(a.z * rs * wv.z); o.w = f2bf(a.w * rs * wv.w);
  ((ushort4*)(xn + (size_t)n * kD))[t] = o;
}

// ---------------------------------------------------------------- GEMM BM=128,BK=32 (QKV)
// Round-5 2-phase + 2D XCD chunk. MODE 0: out bf16 = acc + bias
template <int MODE, int BM>
__global__ __launch_bounds__(256) void k_gemm(
    const u16* __restrict__ A, const u16* __restrict__ Bw,
    const float* __restrict__ bias, const void* extra,
    void* outp, int M, int N, int K, int nR, int nC) {
  constexpr int ASEG = BM / 16;
  constexpr int NSEG = ASEG + 8;
  constexpr int WROWS = BM / 2;
  constexpr int MF = BM / 32;
  __shared__ __align__(16) u16 As[2][BM * 32];
  __shared__ __align__(16) u16 Bs[2][128 * 32];
  const int tid = threadIdx.x, lane = tid & 63, wv_ = tid >> 6;
  const int lr = lane & 15, lg = lane >> 4;
  const int xcd = blockIdx.x & 7, idx = blockIdx.x >> 3;
  const int xrr = xcd >> 2, xcc = xcd & 3;
  const int r_ = idx % nR, c_ = idx / nR;          // row-fastest
  const int brow = (xrr * nR + r_) * BM, bcol = (xcc * nC + c_) * 128;
  const int wr = wv_ >> 1, wc = wv_ & 1;

  const f32x4 zz = {0.f, 0.f, 0.f, 0.f};
  f32x4 acc[MF][4];
#pragma unroll
  for (int m = 0; m < MF; m++)
#pragma unroll
    for (int n = 0; n < 4; n++) acc[m][n] = zz;

  auto stage = [&](int kt, int buf) {
#pragma unroll
    for (int i = 0; i < NSEG / 4; ++i) {
      const int seg = i * 4 + wv_;
      const int rsub = (seg < ASEG) ? seg : seg - ASEG;
      const int row = rsub * 16 + (lane >> 2), cs = lane & 3;
      if (seg < ASEG) {
        __builtin_amdgcn_global_load_lds(AS1(A + (size_t)(brow + row) * K + kt + cs * 8),
                                         AS3((char*)&As[buf][0] + (size_t)seg * 1024), 16, 0, 0);
      } else {
        __builtin_amdgcn_global_load_lds(AS1(Bw + (size_t)(bcol + row) * K + kt + cs * 8),
                                         AS3((char*)&Bs[buf][0] + (size_t)(seg - ASEG) * 1024), 16, 0, 0);
      }
    }
  };

  stage(0, 0);
  __syncthreads();
  for (int kt = 0; kt < K; kt += 32) {
    const int cur = (kt >> 5) & 1;
    if (kt + 32 < K) stage(kt + 32, cur ^ 1);
    bf16x8 af[MF], bfr[4];
#pragma unroll
    for (int m = 0; m < MF; m++) af[m] = *(const bf16x8*)&As[cur][(wr * WROWS + m * 16 + lr) * 32 + lg * 8];
#pragma unroll
    for (int n = 0; n < 4; n++) bfr[n] = *(const bf16x8*)&Bs[cur][(wc * 64 + n * 16 + lr) * 32 + lg * 8];
#pragma unroll
    for (int m = 0; m < MF; m++)
#pragma unroll
      for (int n = 0; n < 4; n++)
        acc[m][n] = __builtin_amdgcn_mfma_f32_16x16x32_bf16(af[m], bfr[n], acc[m][n], 0, 0, 0);
    __syncthreads();
  }

#pragma unroll
  for (int m = 0; m < MF; m++) {
    const int row0 = brow + wr * WROWS + m * 16 + lg * 4;
#pragma unroll
    for (int n = 0; n < 4; n++) {
      const int col = bcol + wc * 64 + n * 16 + lr;
      const float bv = bias[col];
#pragma unroll
      for (int r = 0; r < 4; r++) {
        const size_t idx2 = (size_t)(row0 + r) * N + col;
        float v = acc[m][n][r] + bv;
        if (MODE == 0) {
          ((u16*)outp)[idx2] = f2bf(v);
        } else {
          ((float*)outp)[idx2] = v + ((const float*)extra)[idx2];
        }
      }
    }
  }
}

// ---------------------------------------------------------------- GEMM BM=64,BK=64 (O-proj, out-proj)
// Halves barrier count vs BK=32 (16 MFMA + 6 gloads per barrier). 128B LDS rows would be a
// 16-way bank conflict => XOR-swizzle: linear gload_lds dest + pre-swizzled global source
// (chunk (lane&7)^(lane>>3)) + swizzled fragment reads (rule 21 / attn-K proven pattern).
// MODE 1: out fp32 = acc + bias + f32 extra[idx]
template <int MODE>
__global__ __launch_bounds__(256) void k_gemm64(
    const u16* __restrict__ A, const u16* __restrict__ Bw,
    const float* __restrict__ bias, const void* extra,
    void* outp, int M, int N, int K, int nR, int nC) {
  __shared__ __align__(16) u16 As[2][64 * 64];    // [row][64] byte=row*128+c ^ ((row&7)<<4)
  __shared__ __align__(16) u16 Bs[2][128 * 64];
  const int tid = threadIdx.x, lane = tid & 63, wv_ = tid >> 6;
  const int lr = lane & 15, lg = lane >> 4;
  const int xcd = blockIdx.x & 7, idx = blockIdx.x >> 3;
  const int xrr = xcd >> 2, xcc = xcd & 3;
  const int r_ = idx % nR, c_ = idx / nR;
  const int brow = (xrr * nR + r_) * 64, bcol = (xcc * nC + c_) * 128;
  const int wr = wv_ >> 1, wc = wv_ & 1;

  const f32x4 zz = {0.f, 0.f, 0.f, 0.f};
  f32x4 acc[2][4];
#pragma unroll
  for (int m = 0; m < 2; m++)
#pragma unroll
    for (int n = 0; n < 4; n++) acc[m][n] = zz;

  // per-lane pre-swizzled source chunk: row sub = lane>>3, chunk = (lane&7)^(lane>>3)
  const int lrow = lane >> 3;
  const int lch = ((lane & 7) ^ lrow) * 8;
  auto stage = [&](int kt, int buf) {
#pragma unroll
    for (int i = 0; i < 6; ++i) {
      const int seg = i * 4 + wv_;                 // 0..23 ; A:0-7, B:8-23
      const int rsub = (seg < 8) ? seg : seg - 8;
      const int row = rsub * 8 + lrow;
      if (seg < 8) {
        __builtin_amdgcn_global_load_lds(AS1(A + (size_t)(brow + row) * K + kt + lch),
                                         AS3((char*)&As[buf][0] + (size_t)seg * 1024), 16, 0, 0);
      } else {
        __builtin_amdgcn_global_load_lds(AS1(Bw + (size_t)(bcol + row) * K + kt + lch),
                                         AS3((char*)&Bs[buf][0] + (size_t)(seg - 8) * 1024), 16, 0, 0);
      }
    }
  };

  stage(0, 0);
  __syncthreads();
  for (int kt = 0; kt < K; kt += 64) {
    const int cur = (kt >> 6) & 1;
    if (kt + 64 < K) stage(kt + 64, cur ^ 1);
    bf16x8 af[2][2];
#pragma unroll
    for (int m = 0; m < 2; m++)
#pragma unroll
      for (int ks = 0; ks < 2; ks++) {
        const int row = wr * 32 + m * 16 + lr;
        const int bo = (row * 128 + (ks * 32 + lg * 8) * 2) ^ ((row & 7) << 4);
        af[m][ks] = *(const bf16x8*)((const char*)&As[cur][0] + bo);
      }
#pragma unroll
    for (int n = 0; n < 4; n++) {
      const int row = wc * 64 + n * 16 + lr;
      const int bo0 = (row * 128 + (lg * 8) * 2) ^ ((row & 7) << 4);
      const int bo1 = (row * 128 + (32 + lg * 8) * 2) ^ ((row & 7) << 4);
      bf16x8 b0 = *(const bf16x8*)((const char*)&Bs[cur][0] + bo0);
      bf16x8 b1 = *(const bf16x8*)((const char*)&Bs[cur][0] + bo1);
#pragma unroll
      for (int m = 0; m < 2; m++) {
        acc[m][n] = __builtin_amdgcn_mfma_f32_16x16x32_bf16(af[m][0], b0, acc[m][n], 0, 0, 0);
        acc[m][n] = __builtin_amdgcn_mfma_f32_16x16x32_bf16(af[m][1], b1, acc[m][n], 0, 0, 0);
      }
    }
    __syncthreads();
  }

#pragma unroll
  for (int m = 0; m < 2; m++) {
    const int row0 = brow + wr * 32 + m * 16 + lg * 4;
#pragma unroll
    for (int n = 0; n < 4; n++) {
      const int col = bcol + wc * 64 + n * 16 + lr;
      const float bv = bias[col];
#pragma unroll
      for (int r = 0; r < 4; r++) {
        const size_t idx2 = (size_t)(row0 + r) * N + col;
        float v = acc[m][n][r] + bv;
        ((float*)outp)[idx2] = v + ((const float*)extra)[idx2];
      }
    }
  }
}

// ---------------------------------------------------------------- fused MLP in+gate GEMM (round-9 verified)
__global__ __launch_bounds__(256, 2) void k_mlp(
    const u16* __restrict__ A, const u16* __restrict__ Bi, const u16* __restrict__ Bg,
    const float* __restrict__ bias_i, const float* __restrict__ bias_g,
    u16* __restrict__ outp, int M, int N, int K) {
  __shared__ __align__(16) u16 AsT[2][128 * 32];
  __shared__ __align__(16) u16 BiT[2][128 * 32];
  __shared__ __align__(16) u16 BgT[2][128 * 32];
  const int tid = threadIdx.x, lane = tid & 63, wv_ = tid >> 6;
  const int lr = lane & 15, lg = lane >> 4;
  const int xcd = blockIdx.x & 7, idx = blockIdx.x >> 3;
  const int xrr = xcd >> 2, xcc = xcd & 3;
  const int r_ = idx & 15, c_ = idx >> 4;          // 16 rows x 7 cols, row-fastest
  const int brow = (xrr * 16 + r_) * 128, bcol = (xcc * 7 + c_) * 128;
  const int wr = wv_ >> 1, wc = wv_ & 1;

  const f32x4 zz = {0.f, 0.f, 0.f, 0.f};
  f32x4 accI[4][4], accG[4][4];
#pragma unroll
  for (int m = 0; m < 4; m++)
#pragma unroll
    for (int n = 0; n < 4; n++) { accI[m][n] = zz; accG[m][n] = zz; }

  auto stage = [&](int kt, int buf) {
#pragma unroll
    for (int i = 0; i < 6; ++i) {
      const int seg = i * 4 + wv_;
      const int rsub = seg & 7;
      const int row = rsub * 16 + (lane >> 2), cs = lane & 3;
      const u16* src = (i < 2) ? A : (i < 4 ? Bi : Bg);
      char* dst = (i < 2) ? (char*)&AsT[buf][0] : (i < 4 ? (char*)&BiT[buf][0] : (char*)&BgT[buf][0]);
      __builtin_amdgcn_global_load_lds(
          AS1(src + (size_t)((i < 2 ? brow : bcol) + row) * K + kt + cs * 8),
          AS3(dst + (size_t)rsub * 1024), 16, 0, 0);
    }
  };

  stage(0, 0);
  __syncthreads();
  for (int kt = 0; kt < K; kt += 32) {
    const int cur = (kt >> 5) & 1;
    if (kt + 32 < K) stage(kt + 32, cur ^ 1);
    bf16x8 af[4], bfi[4], bfg[4];
#pragma unroll
    for (int m = 0; m < 4; m++) af[m] = *(const bf16x8*)&AsT[cur][(wr * 64 + m * 16 + lr) * 32 + lg * 8];
#pragma unroll
    for (int n = 0; n < 4; n++) {
      bfi[n] = *(const bf16x8*)&BiT[cur][(wc * 64 + n * 16 + lr) * 32 + lg * 8];
      bfg[n] = *(const bf16x8*)&BgT[cur][(wc * 64 + n * 16 + lr) * 32 + lg * 8];
    }
#pragma unroll
    for (int m = 0; m < 4; m++)
#pragma unroll
      for (int n = 0; n < 4; n++) {
        accI[m][n] = __builtin_amdgcn_mfma_f32_16x16x32_bf16(af[m], bfi[n], accI[m][n], 0, 0, 0);
        accG[m][n] = __builtin_amdgcn_mfma_f32_16x16x32_bf16(af[m], bfg[n], accG[m][n], 0, 0, 0);
      }
    __syncthreads();
  }

#pragma unroll
  for (int m = 0; m < 4; m++) {
    const int row0 = brow + wr * 64 + m * 16 + lg * 4;
#pragma unroll
    for (int n = 0; n < 4; n++) {
      const int col = bcol + wc * 64 + n * 16 + lr;
      const float bi = bias_i[col], bg = bias_g[col];
#pragma unroll
      for (int r = 0; r < 4; r++) {
        const float vi = accI[m][n][r] + bi;
        const float vg = accG[m][n][r] + bg;
        const float g = vg / (1.0f + __expf(-vg));
        outp[(size_t)(row0 + r) * N + col] = f2bf(g * vi);
      }
    }
  }
}

// ---------------------------------------------------------------- flash attention (causal, paired q-blocks, 8 waves)
// + T13 defer-max: skip alpha-rescale when no row's max grew by >8.
__global__ __launch_bounds__(512) void k_attn(
    const u16* __restrict__ qkv, u16* __restrict__ attn_o) {
  __shared__ __align__(16) u16 Ks[2][64 * 64];
  __shared__ __align__(16) u16 Vt[2][64 * 64];
  __shared__ __align__(16) u16 Pl[8][16 * 64];

  const int tid = threadIdx.x, lane = tid & 63, w = tid >> 6;
  const int g = w >> 2, wi = w & 3;
  const int lr = lane & 15, lg = lane >> 4;
  const int bid = blockIdx.x;
  const int half = bid >> 8, rr = bid & 255;
  const int praw = rr & 15;
  const int p = half ? 15 - praw : praw;
  const int bh = (rr >> 4) | (half << 4);
  const int b = bh >> 4, h = bh & 15;
  const int qb = g == 0 ? 31 - p : p;
  const size_t base = (size_t)b * kS;
  const f32x4 zz = {0.f, 0.f, 0.f, 0.f};
  bf16x8 vones;
#pragma unroll
  for (int j = 0; j < 8; j++) vones[j] = (short)0x3F80;

  bf16x8 qf[2];
#pragma unroll
  for (int ks = 0; ks < 2; ks++)
    qf[ks] = *(const bf16x8*)&qkv[(base + qb * 64 + wi * 16 + lr) * 3072 + h * 64 + ks * 32 + lg * 8];

  f32x4 oacc[4], lacc = zz;
  float mrow[4];
#pragma unroll
  for (int nb = 0; nb < 4; nb++) oacc[nb] = zz;
#pragma unroll
  for (int r = 0; r < 4; r++) mrow[r] = -1e30f;

  const int kvloc = (w << 3) + (lane >> 3);
  const int kchv = ((lane & 7) ^ (lane >> 3)) * 8;
  auto issueK = [&](int t, int buf) {
    __builtin_amdgcn_global_load_lds(
        AS1(qkv + (base + t * 64 + kvloc) * 3072 + 1024 + h * 64 + kchv),
        AS3((char*)&Ks[buf][0] + w * 1024 + (size_t)lane * 16), 16, 0, 0);
  };
  const int srow = tid >> 3, dc = (tid & 7) * 8;
  int4 vr;
  auto issueV = [&](int t) {
    vr = *(const int4*)&qkv[(base + t * 64 + srow) * 3072 + 2048 + h * 64 + dc];
  };
  auto commitV = [&](int buf) {
    char* vb = (char*)&Vt[buf][0];
    const u16* ve = (const u16*)&vr;
#pragma unroll
    for (int j = 0; j < 8; j++) {
      const int d = dc + j;
      *(u16*)(vb + ((d * 128 + srow * 2) ^ ((d & 7) << 4))) = ve[j];
    }
  };

  auto compute = [&](int t, int buf) {
    const char* kbuf = (const char*)&Ks[buf][0];
    const char* vbuf = (const char*)&Vt[buf][0];
    const bool masked = (t == qb);
    f32x4 sc[4];
#pragma unroll
    for (int hn = 0; hn < 4; hn++) sc[hn] = zz;
#pragma unroll
    for (int hn = 0; hn < 4; hn++) {
      const int krow = hn * 16 + lr;
#pragma unroll
      for (int ks = 0; ks < 2; ks++) {
        const int bo = (krow * 128 + (ks * 32 + lg * 8) * 2) ^ ((krow & 7) << 4);
        bf16x8 kf = *(const bf16x8*)(kbuf + bo);
        sc[hn] = __builtin_amdgcn_mfma_f32_16x16x32_bf16(qf[ks], kf, sc[hn], 0, 0, 0);
      }
    }
    // scale + mask + row-max; defer-max (T13): rescale only if some row grew >8
    float nm[4];
    bool needv = false;
#pragma unroll
    for (int r = 0; r < 4; r++) {
      const int qa = qb * 64 + wi * 16 + lg * 4 + r;
      float s0 = sc[0][r] * 0.125f, s1 = sc[1][r] * 0.125f;
      float s2 = sc[2][r] * 0.125f, s3 = sc[3][r] * 0.125f;
      if (masked) {
        if (t * 64 + lr > qa) s0 = -1e30f;
        if (t * 64 + 16 + lr > qa) s1 = -1e30f;
        if (t * 64 + 32 + lr > qa) s2 = -1e30f;
        if (t * 64 + 48 + lr > qa) s3 = -1e30f;
      }
      sc[0][r] = s0; sc[1][r] = s1; sc[2][r] = s2; sc[3][r] = s3;
      nm[r] = rowmax16(fmaxf(fmaxf(s0, s1), fmaxf(s2, s3)));
      needv |= (nm[r] > mrow[r] + 8.0f);
    }
    if (__any(needv)) {
      float alpha[4];
#pragma unroll
      for (int r = 0; r < 4; r++) {
        const float mnew = fmaxf(mrow[r], nm[r]);
        alpha[r] = __expf(mrow[r] - mnew);
        mrow[r] = mnew;
      }
#pragma unroll
      for (int nb = 0; nb < 4; nb++)
#pragma unroll
        for (int r = 0; r < 4; r++) oacc[nb][r] *= alpha[r];
#pragma unroll
      for (int r = 0; r < 4; r++) lacc[r] *= alpha[r];
    }
#pragma unroll
    for (int hn = 0; hn < 4; hn++)
#pragma unroll
      for (int r = 0; r < 4; r++) sc[hn][r] = __expf(sc[hn][r] - mrow[r]);
    char* pw = (char*)&Pl[w][0];
#pragma unroll
    for (int hn = 0; hn < 4; hn++)
#pragma unroll
      for (int r = 0; r < 4; r++) {
        const int prow = lg * 4 + r, pcol = hn * 16 + lr;
        *(u16*)(pw + ((prow * 128 + pcol * 2) ^ ((prow & 7) << 4))) = f2bf(sc[hn][r]);
      }
    bf16x8 pf[2];
#pragma unroll
    for (int ks = 0; ks < 2; ks++)
      pf[ks] = *(const bf16x8*)((const char*)pw + ((lr * 128 + (ks * 32 + lg * 8) * 2) ^ ((lr & 7) << 4)));
#pragma unroll
    for (int nb = 0; nb < 4; nb++) {
      const int vrow = nb * 16 + lr;
#pragma unroll
      for (int ks = 0; ks < 2; ks++) {
        const int bo = (vrow * 128 + (ks * 32 + lg * 8) * 2) ^ ((vrow & 7) << 4);
        bf16x8 vf = *(const bf16x8*)(vbuf + bo);
        oacc[nb] = __builtin_amdgcn_mfma_f32_16x16x32_bf16(pf[ks], vf, oacc[nb], 0, 0, 0);
      }
    }
#pragma unroll
    for (int ks = 0; ks < 2; ks++)
      lacc = __builtin_amdgcn_mfma_f32_16x16x32_bf16(pf[ks], vones, lacc, 0, 0, 0);
  };

  const int nt = 32 - p;
  issueV(0);
  issueK(0, 0);
  commitV(0);
  __syncthreads();
  for (int t = 0; t < nt; ++t) {
    const bool hn = (t + 1 < nt);
    const int buf = t & 1;
    if (hn) { issueV(t + 1); issueK(t + 1, buf ^ 1); }
    if (g == 0 || t <= p) compute(t, buf);
    if (hn) commitV(buf ^ 1);
    __syncthreads();
  }

#pragma unroll
  for (int nb = 0; nb < 4; nb++)
#pragma unroll
    for (int r = 0; r < 4; r++) {
      const int q = qb * 64 + wi * 16 + lg * 4 + r;
      attn_o[(base + q) * kD + h * 64 + nb * 16 + lr] = f2bf(oacc[nb][r] / lacc[r]);
    }
}

// ---------------------------------------------------------------- workspace layout (bytes)
constexpr size_t OFF_XR   = 0;                                   // fp32 [4096][1024]
constexpr size_t OFF_XN1  = OFF_XR  + (size_t)kN * kD * 4;       // bf16 [4096][1024]
constexpr size_t OFF_XN2  = OFF_XN1 + (size_t)kN * kD * 2;       // bf16 [4096][1024]
constexpr size_t OFF_W    = OFF_XN2 + (size_t)kN * kD * 2;       // bf16 weight arena
constexpr size_t OFF_BQKV = OFF_W + 15204352ull * 2;             // fp32 [3072]
constexpr size_t OFF_ACT  = OFF_BQKV + 3072 * 4;                 // activation arena

extern "C" void kernel_launch(void* const* d_in, const int* in_sizes, int n_in,
                              void* d_out, int out_size, void* d_ws, size_t ws_size,
                              hipStream_t stream) {
  const float* x     = (const float*)d_in[0];
  const float* pos   = (const float*)d_in[1];
  const float* n1w   = (const float*)d_in[2];
  const float* n2w   = (const float*)d_in[3];
  const float* q_w   = (const float*)d_in[4];
  const float* q_b   = (const float*)d_in[5];
  const float* k_w   = (const float*)d_in[6];
  const float* k_b   = (const float*)d_in[7];
  const float* v_w   = (const float*)d_in[8];
  const float* v_b   = (const float*)d_in[9];
  const float* o_w   = (const float*)d_in[10];
  const float* o_b   = (const float*)d_in[11];
  const float* in_w  = (const float*)d_in[12];
  const float* in_b  = (const float*)d_in[13];
  const float* gate_w= (const float*)d_in[14];
  const float* gate_b= (const float*)d_in[15];
  const float* out_w = (const float*)d_in[16];
  const float* out_b = (const float*)d_in[17];
  float* outf = (float*)d_out;
  char* ws = (char*)d_ws;

  float* xr   = (float*)(ws + OFF_XR);
  u16*   xn1  = (u16*)(ws + OFF_XN1);
  u16*   xn2  = (u16*)(ws + OFF_XN2);
  u16*   W    = (u16*)(ws + OFF_W);
  float* bqkv = (float*)(ws + OFF_BQKV);
  u16*   qkv  = (u16*)(ws + OFF_ACT);
  u16*   attn_o = (u16*)(ws + OFF_ACT + (size_t)kN * 3072 * 2);
  u16*   hb     = (u16*)(ws + OFF_ACT);

  u16* Wq   = W + 0;
  u16* Wo   = W + 3145728;
  u16* Win  = W + 4194304;
  u16* Wg   = W + 7864320;
  u16* Wout = W + 11534336;

  // 1. fused: pos add + RMSNorm1 (blocks 0..4095) ; weight conversion (rest)
  k_prepw<<<kN + 14851, 256, 0, stream>>>(x, pos, n1w, xr, xn1,
                                          q_w, k_w, v_w, o_w, in_w, gate_w, out_w,
                                          q_b, k_b, v_b, W, bqkv);

  // 2. QKV projection -> qkv bf16 [4096][3072]  (XCD 2x4, 16x6 each)
  k_gemm<0, 128><<<768, 256, 0, stream>>>(xn1, Wq, bqkv, nullptr, qkv, kN, 3072, kD, 16, 6);

  // 3. attention
  k_attn<<<512, 512, 0, stream>>>(qkv, attn_o);

  // 4. O projection + residual -> d_out fp32  (BK=64; XCD 2x4, 32x2 each)
  k_gemm64<1><<<512, 256, 0, stream>>>(attn_o, Wo, o_b, xr, outf, kN, kD, kD, 32, 2);

  // 5. RMSNorm2
  k_rms2<<<kN, 256, 0, stream>>>(outf, n2w, xn2);

  // 6. fused MLP in+gate -> hb bf16 [4096][3584]
  k_mlp<<<896, 256, 0, stream>>>(xn2, Win, Wg, in_b, gate_b, hb, kN, kHID, kD);

  // 7. MLP out GEMM + residual -> d_out  (BK=64; XCD 2x4, 32x2 each)
  k_gemm64<1><<<512, 256, 0, stream>>>(hb, Wout, out_b, outf, outf, kN, kD, kHID, 32, 2);
}